// Round 1
// baseline (1819.465 us; speedup 1.0000x reference)
//
#include <hip/hip_runtime.h>
#include <hip/hip_bf16.h>

// Problem: T=512, B=64, N=256, H=64, D=128, P=64.
// Stage 1: x2n = input(32768x128) @ W2n^T(128x256) + b2n          (gemm_xwT)
// Stage 2: 16384 independent LSTM cells scanned over 512 steps    (lstm_scan)
// Stage 3: out = ON(32768x256) @ Wout^T(256x64) + bout            (gemm_xwT)
// Workspace: x2n 32MB + ON 32MB = 64MB of d_ws.

typedef __attribute__((ext_vector_type(4))) float f32x4;
typedef __attribute__((ext_vector_type(4))) short s16x4;
typedef __attribute__((ext_vector_type(8))) short s16x8;

__device__ inline short bf16r(float f) {            // round-to-nearest-even bf16
    unsigned u = __builtin_bit_cast(unsigned, f);
    u += 0x7fffu + ((u >> 16) & 1u);
    return (short)(u >> 16);
}
__device__ inline float sigf(float x) {             // 1/(1+e^-x)
    return __builtin_amdgcn_rcpf(1.f + __builtin_amdgcn_exp2f(x * -1.4426950408889634f));
}
__device__ inline float tanh_fast(float x) {        // 1 - 2/(e^{2x}+1)
    return 1.f - 2.f * __builtin_amdgcn_rcpf(1.f + __builtin_amdgcn_exp2f(x * 2.885390081777927f));
}

#if __has_builtin(__builtin_amdgcn_mfma_f32_16x16x16bf16_1k)
#define HAVE_MFMA16 1
__device__ inline f32x4 mfma16(s16x4 a, s16x4 b, f32x4 c) {
    return __builtin_amdgcn_mfma_f32_16x16x16bf16_1k(a, b, c, 0, 0, 0);
}
#else
#define HAVE_MFMA16 0
__device__ inline s16x8 cat8(s16x4 a, s16x4 b) {
    s16x8 r;
    r[0]=a[0]; r[1]=a[1]; r[2]=a[2]; r[3]=a[3];
    r[4]=b[0]; r[5]=b[1]; r[6]=b[2]; r[7]=b[3];
    return r;
}
#endif

// ---------------------------------------------------------------------------
// Generic fp32 GEMM: Out(MxN) = X(MxK) @ Wt(NxK)^T + bias(N).  M%64==0,
// N%64==0, K%32==0.  grid = (M/64, N/64), block = 256.
// ---------------------------------------------------------------------------
__global__ __launch_bounds__(256) void gemm_xwT(
    const float* __restrict__ X, const float* __restrict__ Wt,
    const float* __restrict__ bias, float* __restrict__ Out,
    int N, int K)
{
    __shared__ float Xs[32][68];   // [k][m], pad 68 keeps 16B alignment, spreads banks
    __shared__ float Ws[32][68];   // [k][n]
    const int tid = threadIdx.x;
    const int tx = tid & 15, ty = tid >> 4;
    const int m0 = blockIdx.x * 64, n0 = blockIdx.y * 64;
    const int kq = tid & 7, mr = tid >> 3;

    float acc[4][4];
#pragma unroll
    for (int i = 0; i < 4; ++i)
#pragma unroll
        for (int j = 0; j < 4; ++j) acc[i][j] = 0.f;

    for (int kc = 0; kc < K; kc += 32) {
#pragma unroll
        for (int rr = 0; rr < 2; ++rr) {
            const int m = mr + rr * 32;
            f32x4 xv = *(const f32x4*)(X + (size_t)(m0 + m) * K + kc + kq * 4);
            f32x4 wv = *(const f32x4*)(Wt + (size_t)(n0 + m) * K + kc + kq * 4);
#pragma unroll
            for (int j = 0; j < 4; ++j) { Xs[kq*4 + j][m] = xv[j]; Ws[kq*4 + j][m] = wv[j]; }
        }
        __syncthreads();
#pragma unroll
        for (int k = 0; k < 32; ++k) {
            f32x4 a = *(const f32x4*)&Xs[k][ty * 4];
            f32x4 b = *(const f32x4*)&Ws[k][tx * 4];
#pragma unroll
            for (int i = 0; i < 4; ++i)
#pragma unroll
                for (int j = 0; j < 4; ++j)
                    acc[i][j] = __builtin_fmaf(a[i], b[j], acc[i][j]);
        }
        __syncthreads();
    }
    f32x4 bv = *(const f32x4*)(bias + n0 + tx * 4);
#pragma unroll
    for (int i = 0; i < 4; ++i) {
        f32x4 o;
#pragma unroll
        for (int j = 0; j < 4; ++j) o[j] = acc[i][j] + bv[j];
        *(f32x4*)(Out + (size_t)(m0 + ty * 4 + i) * N + n0 + tx * 4) = o;
    }
}

// ---------------------------------------------------------------------------
// Recurrent scan.  256 blocks x 4 waves; each wave owns 16 cells for all 512
// steps.  Per step: gates(16x256) = h(16x64) @ W_hh^T via 64 x mfma 16x16x16
// bf16 (W_hh fragments register-resident), fp32 nonlinearities, h->bf16->LDS
// (wave-private tile, XOR-swizzled, no barriers), fused softplus + gain.
// MFMA layouts (classic 16x16x16 family):
//   A: lane l holds A[l&15][4*(l>>4)+e]     (per 16k sub-step)
//   B: lane l holds B[4*(l>>4)+e][l&15]
//   D: lane l reg e holds D[4*(l>>4)+e][l&15]
// ---------------------------------------------------------------------------
__global__ __launch_bounds__(256, 1) void lstm_scan(
    const float* __restrict__ x2n,   // [512][16384]
    const float* __restrict__ W_hh,  // [256][64]
    const float* __restrict__ w_ih,  // [256]
    const float* __restrict__ b_ih,  // [256]
    const float* __restrict__ b_hh,  // [256]
    const float* __restrict__ wg,    // [64]
    const float* __restrict__ bg,    // [1]
    float* __restrict__ ON)          // [512][16384]
{
    __shared__ short hT[4][1024];    // per wave: h tile [cell16][64] bf16, swizzled
    const int tid = threadIdx.x;
    const int wv = tid >> 6, lane = tid & 63;
    const int c15 = lane & 15, g4 = lane >> 4;
    const int cellbase = (blockIdx.x * 4 + wv) * 16;
    short* lds = &hT[wv][0];

    // zero the h tile (h0 = 0); wave-private, no barrier needed
#pragma unroll
    for (int i = 0; i < 16; ++i) lds[lane + i * 64] = 0;

    // B fragments: bfrag[ks][nt][e] = W_hh[16nt + c15][16ks + 4*g4 + e]
    s16x4 bfrag[4][16];
#pragma unroll
    for (int nt = 0; nt < 16; ++nt) {
        const float* wrow = W_hh + (size_t)(nt * 16 + c15) * 64;
#pragma unroll
        for (int ks = 0; ks < 4; ++ks) {
            f32x4 w = *(const f32x4*)(wrow + ks * 16 + g4 * 4);
            s16x4 bb;
#pragma unroll
            for (int e = 0; e < 4; ++e) bb[e] = bf16r(w[e]);
            bfrag[ks][nt] = bb;
        }
    }

    float wih_l[16], bias_l[16];
#pragma unroll
    for (int nt = 0; nt < 16; ++nt) {
        wih_l[nt]  = w_ih[nt * 16 + c15];
        bias_l[nt] = b_ih[nt * 16 + c15] + b_hh[nt * 16 + c15];
    }
    float wg_l[4];
#pragma unroll
    for (int q = 0; q < 4; ++q) wg_l[q] = wg[q * 16 + c15];
    const float bg0 = bg[0];

    f32x4 cst[4];
#pragma unroll
    for (int q = 0; q < 4; ++q) cst[q] = (f32x4){0.f, 0.f, 0.f, 0.f};
    f32x4 gp1 = {0.f, 0.f, 0.f, 0.f}, gp2 = {0.f, 0.f, 0.f, 0.f};

    const int sw_r = (c15 & 7) << 4;      // read swizzle (byte XOR within a row)
    int wbase[4], wsw[4];
#pragma unroll
    for (int e = 0; e < 4; ++e) {
        const int cell = g4 * 4 + e;
        wbase[e] = cell * 64;             // short index of row start
        wsw[e]   = (cell & 7) << 4;       // write swizzle for that row
    }

    for (int t = 0; t < 512; ++t) {
        // A fragments: af[ks] lane l -> h[c15][16ks + 4*g4 + e]
        s16x4 af[4];
#pragma unroll
        for (int ks = 0; ks < 4; ++ks) {
            const int boff = ((ks * 32 + g4 * 8) ^ sw_r) >> 1;   // bytes -> shorts
            af[ks] = *(const s16x4*)(lds + c15 * 64 + boff);
        }

        // x values for this wave's 4 cell-rows (same float4 across a 16-lane group)
        f32x4 xv = *(const f32x4*)(x2n + (size_t)t * 16384 + cellbase + g4 * 4);

        // acc init = x*w_ih + bias  (then MFMA accumulates h@W_hh^T on top)
        f32x4 acc[16];
#pragma unroll
        for (int nt = 0; nt < 16; ++nt) {
            f32x4 a;
#pragma unroll
            for (int e = 0; e < 4; ++e) a[e] = __builtin_fmaf(xv[e], wih_l[nt], bias_l[nt]);
            acc[nt] = a;
        }

#if HAVE_MFMA16
#pragma unroll
        for (int ks = 0; ks < 4; ++ks)
#pragma unroll
            for (int nt = 0; nt < 16; ++nt)
                acc[nt] = mfma16(af[ks], bfrag[ks][nt], acc[nt]);
#else
        // 16x16x32 with two stacked 16x16x16 halves (elems 0-3 = k, 4-7 = k+16)
#pragma unroll
        for (int kp = 0; kp < 4; kp += 2) {
            s16x8 a8 = cat8(af[kp], af[kp + 1]);
#pragma unroll
            for (int nt = 0; nt < 16; ++nt) {
                s16x8 b8 = cat8(bfrag[kp][nt], bfrag[kp + 1][nt]);
                acc[nt] = __builtin_amdgcn_mfma_f32_16x16x32_bf16(a8, b8, acc[nt], 0, 0, 0);
            }
        }
#endif

        // nonlinearities: gate g=16nt+c15; j = g&63 => j-group q=nt&3, type=nt>>2
        f32x4 hv[4];
#pragma unroll
        for (int q = 0; q < 4; ++q) {
            f32x4 cn, hn;
#pragma unroll
            for (int e = 0; e < 4; ++e) {
                const float iv = acc[q][e], fv = acc[q + 4][e];
                const float gv = acc[q + 8][e], ov = acc[q + 12][e];
                const float c2 = sigf(fv) * cst[q][e] + sigf(iv) * tanh_fast(gv);
                cn[e] = c2;
                hn[e] = sigf(ov) * tanh_fast(c2);
            }
            cst[q] = cn;
            hv[q]  = hn;
        }

        // g_t = sum_j wg[j]*h[cell][j] + bg : partial over q, reduce over 16 lanes
        f32x4 gs = {0.f, 0.f, 0.f, 0.f};
#pragma unroll
        for (int q = 0; q < 4; ++q)
#pragma unroll
            for (int e = 0; e < 4; ++e) gs[e] = __builtin_fmaf(hv[q][e], wg_l[q], gs[e]);
#pragma unroll
        for (int m = 1; m < 16; m <<= 1) {
#pragma unroll
            for (int e = 0; e < 4; ++e) gs[e] += __shfl_xor(gs[e], m, 64);
        }
#pragma unroll
        for (int e = 0; e < 4; ++e) gs[e] += bg0;

        // write h (bf16, RNE) back to the swizzled LDS tile
#pragma unroll
        for (int q = 0; q < 4; ++q)
#pragma unroll
            for (int e = 0; e < 4; ++e) {
                const int idx = wbase[e] + (((q * 32 + c15 * 2) ^ wsw[e]) >> 1);
                lds[idx] = bf16r(hv[q][e]);
            }

        // out[t,cell] = gain * softplus(x-1); gain = g_t (t==0), 1 (t==1), g_{t-2}
#pragma unroll
        for (int e = 0; e < 4; ++e) {
            if (c15 == e) {
                const float gain = (t == 0) ? gs[e] : ((t == 1) ? 1.f : gp2[e]);
                const float x1 = xv[e] - 1.f;
                const float spv = fmaxf(x1, 0.f) + log1pf(__expf(-fabsf(x1)));
                ON[(size_t)t * 16384 + cellbase + g4 * 4 + e] = gain * spv;
            }
        }
        gp2 = gp1;
        gp1 = gs;
    }
}

extern "C" void kernel_launch(void* const* d_in, const int* in_sizes, int n_in,
                              void* d_out, int out_size, void* d_ws, size_t ws_size,
                              hipStream_t stream)
{
    const float* input = (const float*)d_in[0];   // [512][64][128]
    const float* W2n   = (const float*)d_in[1];   // [256][128]
    const float* b2n   = (const float*)d_in[2];   // [256]
    const float* W_ih  = (const float*)d_in[3];   // [256] (4H x 1)
    const float* W_hh  = (const float*)d_in[4];   // [256][64]
    const float* b_ih  = (const float*)d_in[5];   // [256]
    const float* b_hh  = (const float*)d_in[6];   // [256]
    const float* Wg    = (const float*)d_in[7];   // [64]  (1 x H)
    const float* bg    = (const float*)d_in[8];   // [1]
    const float* Wout  = (const float*)d_in[9];   // [64][256]
    const float* bout  = (const float*)d_in[10];  // [64]

    float* x2n = (float*)d_ws;                          // 512*16384 f32 = 32MB
    float* ON  = x2n + (size_t)512 * 16384;             // another 32MB (needs ws >= 64MB)

    // Stage 1: x2n = input @ W2n^T + b2n   (M=32768, N=256, K=128)
    gemm_xwT<<<dim3(512, 4), 256, 0, stream>>>(input, W2n, b2n, x2n, 256, 128);

    // Stage 2: recurrent scan -> ON
    lstm_scan<<<256, 256, 0, stream>>>(x2n, W_hh, W_ih, b_ih, b_hh, Wg, bg, ON);

    // Stage 3: out = ON @ Wout^T + bout    (M=32768, N=64, K=256)
    gemm_xwT<<<dim3(512, 1), 256, 0, stream>>>(ON, Wout, bout, (float*)d_out, 64, 256);
}

// Round 2
// 885.096 us; speedup vs baseline: 2.0557x; 2.0557x over previous
//
#include <hip/hip_runtime.h>
#include <hip/hip_bf16.h>

// Problem: T=512, B=64, N=256, H=64, D=128, P=64.
// Stage 1: x2n = input(32768x128) @ W2n^T(128x256) + b2n          (gemm_xwT)
// Stage 2: 16384 independent LSTM cells scanned over 512 steps    (lstm_scan)
// Stage 3: out = ON(32768x256) @ Wout^T(256x64) + bout            (gemm_xwT)
// Workspace: x2n 32MB + ON 32MB = 64MB of d_ws.
//
// Scan structure (swapped-operand MFMA, zero LDS):
//   gates^T = [W_hh | w_ih,bias slices] @ [h ; x,1]^T  per 16-cell wave.
//   D-layout puts all gates of cell (lane&15) in one lane; the produced
//   h[c15][q*16+4*g4+e] is exactly the B-fragment layout for the next step,
//   so h_t round-trips entirely in registers (bf16), no LDS, no shuffles.

typedef __attribute__((ext_vector_type(4))) float f32x4;
typedef __attribute__((ext_vector_type(4))) short s16x4;
typedef __attribute__((ext_vector_type(8))) short s16x8;

__device__ inline short bf16r(float f) {            // round-to-nearest-even bf16
    unsigned u = __builtin_bit_cast(unsigned, f);
    u += 0x7fffu + ((u >> 16) & 1u);
    return (short)(u >> 16);
}
__device__ inline float bf2f(short s) {
    unsigned u = ((unsigned)(unsigned short)s) << 16;
    return __builtin_bit_cast(float, u);
}
__device__ inline float sigf(float x) {             // 1/(1+e^-x)
    return __builtin_amdgcn_rcpf(1.f + __builtin_amdgcn_exp2f(x * -1.4426950408889634f));
}
__device__ inline float tanh_fast(float x) {        // 1 - 2/(e^{2x}+1)
    return 1.f - 2.f * __builtin_amdgcn_rcpf(1.f + __builtin_amdgcn_exp2f(x * 2.885390081777927f));
}

#if __has_builtin(__builtin_amdgcn_mfma_f32_16x16x16bf16_1k)
#define HAVE_MFMA16 1
__device__ inline f32x4 mfma16(s16x4 a, s16x4 b, f32x4 c) {
    return __builtin_amdgcn_mfma_f32_16x16x16bf16_1k(a, b, c, 0, 0, 0);
}
#else
#define HAVE_MFMA16 0
__device__ inline s16x8 cat8(s16x4 a, s16x4 b) {
    s16x8 r;
    r[0]=a[0]; r[1]=a[1]; r[2]=a[2]; r[3]=a[3];
    r[4]=b[0]; r[5]=b[1]; r[6]=b[2]; r[7]=b[3];
    return r;
}
#endif

// ---------------------------------------------------------------------------
// Generic fp32 GEMM: Out(MxN) = X(MxK) @ Wt(NxK)^T + bias(N).  M%64==0,
// N%64==0, K%32==0.  grid = (M/64, N/64), block = 256.
// ---------------------------------------------------------------------------
__global__ __launch_bounds__(256) void gemm_xwT(
    const float* __restrict__ X, const float* __restrict__ Wt,
    const float* __restrict__ bias, float* __restrict__ Out,
    int N, int K)
{
    __shared__ float Xs[32][68];
    __shared__ float Ws[32][68];
    const int tid = threadIdx.x;
    const int tx = tid & 15, ty = tid >> 4;
    const int m0 = blockIdx.x * 64, n0 = blockIdx.y * 64;
    const int kq = tid & 7, mr = tid >> 3;

    float acc[4][4];
#pragma unroll
    for (int i = 0; i < 4; ++i)
#pragma unroll
        for (int j = 0; j < 4; ++j) acc[i][j] = 0.f;

    for (int kc = 0; kc < K; kc += 32) {
#pragma unroll
        for (int rr = 0; rr < 2; ++rr) {
            const int m = mr + rr * 32;
            f32x4 xv = *(const f32x4*)(X + (size_t)(m0 + m) * K + kc + kq * 4);
            f32x4 wv = *(const f32x4*)(Wt + (size_t)(n0 + m) * K + kc + kq * 4);
#pragma unroll
            for (int j = 0; j < 4; ++j) { Xs[kq*4 + j][m] = xv[j]; Ws[kq*4 + j][m] = wv[j]; }
        }
        __syncthreads();
#pragma unroll
        for (int k = 0; k < 32; ++k) {
            f32x4 a = *(const f32x4*)&Xs[k][ty * 4];
            f32x4 b = *(const f32x4*)&Ws[k][tx * 4];
#pragma unroll
            for (int i = 0; i < 4; ++i)
#pragma unroll
                for (int j = 0; j < 4; ++j)
                    acc[i][j] = __builtin_fmaf(a[i], b[j], acc[i][j]);
        }
        __syncthreads();
    }
    f32x4 bv = *(const f32x4*)(bias + n0 + tx * 4);
#pragma unroll
    for (int i = 0; i < 4; ++i) {
        f32x4 o;
#pragma unroll
        for (int j = 0; j < 4; ++j) o[j] = acc[i][j] + bv[j];
        *(f32x4*)(Out + (size_t)(m0 + ty * 4 + i) * N + n0 + tx * 4) = o;
    }
}

// ---------------------------------------------------------------------------
// Recurrent scan, register-only h.  1024 blocks x 64 threads; each wave owns
// 16 cells (cell = cellbase + (lane&15)) for all 512 steps.
//
// MFMA layouts (16x16x16 bf16 family), lane l, c15=l&15, g4=l>>4:
//   A: lane holds A[c15][16ks + 4*g4 + e]
//   B: lane holds B[16ks + 4*g4 + e][c15]
//   D: lane reg e holds D[4*g4 + e][c15]
//
// Per step: acc[nt] (nt=0..15 gate tiles) = ext-slice MFMA (x,bias) + 4 K-
// slices of W_hh @ h^T.  Lane (g4,c15) reg e = gate nt*16+4g4+e of cell c15;
// type=nt>>2, j=(nt&3)*16+4g4+e.  New h values land exactly in next step's
// B-fragment slots: bh[q][e] = bf16(h[c15][q*16+4g4+e]).
// ---------------------------------------------------------------------------
__global__ __launch_bounds__(64, 1) void lstm_scan(
    const float* __restrict__ x2n,   // [512][16384]
    const float* __restrict__ W_hh,  // [256][64]
    const float* __restrict__ w_ih,  // [256]
    const float* __restrict__ b_ih,  // [256]
    const float* __restrict__ b_hh,  // [256]
    const float* __restrict__ wg,    // [64]
    const float* __restrict__ bg,    // [1]
    float* __restrict__ ON)          // [512][16384]
{
    const int lane = threadIdx.x & 63;
    const int c15 = lane & 15, g4 = lane >> 4;
    const int cellbase = blockIdx.x * 16;

    // A fragments of W_hh (row = gate nt*16+c15, k = 16ks+4g4+e)
    s16x4 afw[4][16];
#pragma unroll
    for (int nt = 0; nt < 16; ++nt) {
        const float* wrow = W_hh + (size_t)(nt * 16 + c15) * 64;
#pragma unroll
        for (int ks = 0; ks < 4; ++ks) {
            f32x4 w = *(const f32x4*)(wrow + ks * 16 + g4 * 4);
            s16x4 bb;
#pragma unroll
            for (int e = 0; e < 4; ++e) bb[e] = bf16r(w[e]);
            afw[ks][nt] = bb;
        }
    }

    // Extension slice (k=64..79): k64=wh, k65=wh, k66=wl, k67=bias_h, k68=bias_l
    // paired with B-ext (xh, xl, xh, 1, 1).  Exact split: err ~ xl*wl ~ 1e-5.
    s16x4 afx[16];
#pragma unroll
    for (int nt = 0; nt < 16; ++nt) {
        const int g = nt * 16 + c15;
        const float wi = w_ih[g];
        const float bs = b_ih[g] + b_hh[g];
        const short wh = bf16r(wi);
        const short wl = bf16r(wi - bf2f(wh));
        const short bh_ = bf16r(bs);
        const short bl_ = bf16r(bs - bf2f(bh_));
        s16x4 v = (s16x4){0, 0, 0, 0};
        if (g4 == 0) { v[0] = wh; v[1] = wh; v[2] = wl; v[3] = bh_; }
        else if (g4 == 1) { v[0] = bl_; }
        afx[nt] = v;
    }

    // wg, laid out to match hv: wg_l[q][e] = wg[q*16 + 4*g4 + e]
    f32x4 wg_l[4];
#pragma unroll
    for (int q = 0; q < 4; ++q) wg_l[q] = *(const f32x4*)(wg + q * 16 + g4 * 4);
    const float bg0 = bg[0];
    const short one_bf = (short)0x3F80;

    f32x4 cst[4];
    s16x4 bh[4];                      // h_{t-1} as B-fragments (bf16)
#pragma unroll
    for (int q = 0; q < 4; ++q) {
        cst[q] = (f32x4){0.f, 0.f, 0.f, 0.f};
        bh[q] = (s16x4){0, 0, 0, 0};
    }
    float gp1 = 0.f, gp2 = 0.f;

    float xs = x2n[cellbase + c15];   // x for (t=0, cell c15), prefetched

    for (int t = 0; t < 512; ++t) {
        // B extension fragment from x (hi/lo bf16 split)
        const short xh = bf16r(xs);
        const short xl = bf16r(xs - bf2f(xh));
        s16x4 bx = (s16x4){0, 0, 0, 0};
        if (g4 == 0) { bx[0] = xh; bx[1] = xl; bx[2] = xh; bx[3] = one_bf; }
        else if (g4 == 1) { bx[0] = one_bf; }
        const float xs_cur = xs;
        if (t < 511) xs = x2n[(size_t)(t + 1) * 16384 + cellbase + c15]; // prefetch

        // gates^T: ext slice init + 4 K-slices of W_hh @ h^T
        f32x4 acc[16];
        const f32x4 zero4 = (f32x4){0.f, 0.f, 0.f, 0.f};
#if HAVE_MFMA16
#pragma unroll
        for (int nt = 0; nt < 16; ++nt) acc[nt] = mfma16(afx[nt], bx, zero4);
#pragma unroll
        for (int ks = 0; ks < 4; ++ks)
#pragma unroll
            for (int nt = 0; nt < 16; ++nt)
                acc[nt] = mfma16(afw[ks][nt], bh[ks], acc[nt]);
#else
        {
            const s16x4 z4 = (s16x4){0, 0, 0, 0};
            s16x8 bx8 = cat8(bx, z4);
            s16x8 b01 = cat8(bh[0], bh[1]);
            s16x8 b23 = cat8(bh[2], bh[3]);
#pragma unroll
            for (int nt = 0; nt < 16; ++nt) {
                acc[nt] = __builtin_amdgcn_mfma_f32_16x16x32_bf16(cat8(afx[nt], z4), bx8, zero4, 0, 0, 0);
                acc[nt] = __builtin_amdgcn_mfma_f32_16x16x32_bf16(cat8(afw[0][nt], afw[1][nt]), b01, acc[nt], 0, 0, 0);
                acc[nt] = __builtin_amdgcn_mfma_f32_16x16x32_bf16(cat8(afw[2][nt], afw[3][nt]), b23, acc[nt], 0, 0, 0);
            }
        }
#endif

        // nonlinearities; hv[q][e] = h[c15][q*16+4g4+e]
        f32x4 hvf[4];
#pragma unroll
        for (int q = 0; q < 4; ++q) {
            f32x4 cn, hn;
#pragma unroll
            for (int e = 0; e < 4; ++e) {
                const float iv = acc[q][e], fv = acc[q + 4][e];
                const float gv = acc[q + 8][e], ov = acc[q + 12][e];
                const float c2 = sigf(fv) * cst[q][e] + sigf(iv) * tanh_fast(gv);
                cn[e] = c2;
                hn[e] = sigf(ov) * tanh_fast(c2);
            }
            cst[q] = cn;
            hvf[q] = hn;
        }

        // next-step B fragments (register-only h round trip)
#pragma unroll
        for (int q = 0; q < 4; ++q) {
            s16x4 b;
#pragma unroll
            for (int e = 0; e < 4; ++e) b[e] = bf16r(hvf[q][e]);
            bh[q] = b;
        }

        // g_t[c15] = sum_j wg[j] h[c15][j] + bg; partial over (q,e), reduce g4
        float gpart = 0.f;
#pragma unroll
        for (int q = 0; q < 4; ++q)
#pragma unroll
            for (int e = 0; e < 4; ++e)
                gpart = __builtin_fmaf(hvf[q][e], wg_l[q][e], gpart);
        gpart += __shfl_xor(gpart, 16, 64);
        gpart += __shfl_xor(gpart, 32, 64);
        const float gcur = gpart + bg0;

        // out[t,cell] = gain * softplus(x-1); gain = g_t, 1, g_{t-2}
        const float gain = (t == 0) ? gcur : ((t == 1) ? 1.f : gp2);
        const float x1 = xs_cur - 1.f;
        const float sp = fmaxf(x1, 0.f) +
            0.6931471805599453f * __builtin_amdgcn_logf(
                1.f + __builtin_amdgcn_exp2f(-1.4426950408889634f * fabsf(x1)));
        if (g4 == 0) ON[(size_t)t * 16384 + cellbase + c15] = gain * sp;

        gp2 = gp1;
        gp1 = gcur;
    }
}

extern "C" void kernel_launch(void* const* d_in, const int* in_sizes, int n_in,
                              void* d_out, int out_size, void* d_ws, size_t ws_size,
                              hipStream_t stream)
{
    const float* input = (const float*)d_in[0];   // [512][64][128]
    const float* W2n   = (const float*)d_in[1];   // [256][128]
    const float* b2n   = (const float*)d_in[2];   // [256]
    const float* W_ih  = (const float*)d_in[3];   // [256] (4H x 1)
    const float* W_hh  = (const float*)d_in[4];   // [256][64]
    const float* b_ih  = (const float*)d_in[5];   // [256]
    const float* b_hh  = (const float*)d_in[6];   // [256]
    const float* Wg    = (const float*)d_in[7];   // [64]  (1 x H)
    const float* bg    = (const float*)d_in[8];   // [1]
    const float* Wout  = (const float*)d_in[9];   // [64][256]
    const float* bout  = (const float*)d_in[10];  // [64]

    float* x2n = (float*)d_ws;                          // 512*16384 f32 = 32MB
    float* ON  = x2n + (size_t)512 * 16384;             // another 32MB

    // Stage 1: x2n = input @ W2n^T + b2n   (M=32768, N=256, K=128)
    gemm_xwT<<<dim3(512, 4), 256, 0, stream>>>(input, W2n, b2n, x2n, 256, 128);

    // Stage 2: recurrent scan -> ON
    lstm_scan<<<1024, 64, 0, stream>>>(x2n, W_hh, W_ih, b_ih, b_hh, Wg, bg, ON);

    // Stage 3: out = ON @ Wout^T + bout    (M=32768, N=64, K=256)
    gemm_xwT<<<dim3(512, 1), 256, 0, stream>>>(ON, Wout, bout, (float*)d_out, 64, 256);
}